// Round 5
// baseline (239.142 us; speedup 1.0000x reference)
//
#include <hip/hip_runtime.h>

#define RR 4
#define NS 17
#define BB 4
#define CC 128
#define HH 96
#define WW 160
#define HWSZ (HH * WW)

// Block (8,32) = 256 threads = 4 waves. Thread = 1 row x 4 cols (float4 quad).
// Pixel tile 32x32. NO LDS, NO barriers: taps read direct from global, L1-cached
// (channel tile incl. halo = 6.4 KB << 32 KB L1). Channel loop pipelines on
// per-wave vmcnt only — no s_waitcnt vmcnt(0)+s_barrier drain anywhere.
#define TW 32
#define THT 32
#define CCHUNK 16
#define NCHUNK (CC / CCHUNK)   // 8 atomic writers per output

typedef float4 f4;

__global__ __launch_bounds__(256)
void cost_volume_kernel(const float* __restrict__ src,
                        const float* __restrict__ tgt,
                        float* __restrict__ out) {
    const int x  = threadIdx.x;          // 0..7  (quad index)
    const int ty = threadIdx.y;          // 0..31 (row)
    const int w0 = blockIdx.x * TW;
    const int h0 = blockIdx.y * THT;
    const int b  = blockIdx.z & 3;
    const int c0 = (blockIdx.z >> 2) * CCHUNK;

    const int r  = h0 + ty;              // global row (always < HH)
    const int cb = w0 + 4 * x;           // quad's first col (always <= WW-4)

    const float* tb = tgt + ((size_t)b * CC + c0) * HWSZ;
    const float* sp = src + ((size_t)b * CC + c0) * HWSZ + (size_t)r * WW + cb;

    // Channel-invariant predicates. Halo = 4 = f4 width -> segs all-in or all-out.
    const bool pL = (cb >= 4);           // left row seg [cb-4, cb-1]
    const bool pR = (cb + 8 <= WW);      // right row seg [cb+4, cb+7]
    bool pu[RR + 1], pd[RR + 1];
#pragma unroll
    for (int i = 1; i <= RR; ++i) {
        pu[i] = (r - i) >= 0;
        pd[i] = (r + i) < HH;
    }

    const f4 z4 = make_float4(0.f, 0.f, 0.f, 0.f);
    const int oM = r * WW + cb;          // center quad offset within channel plane

    float acc[NS][4];
#pragma unroll
    for (int s = 0; s < NS; ++s)
#pragma unroll
        for (int j = 0; j < 4; ++j) acc[s][j] = 0.f;

#pragma unroll 2
    for (int c = 0; c < CCHUNK; ++c) {
        const float* tp = tb + (size_t)c * HWSZ;

        f4 s4 = *(const f4*)(sp + (size_t)c * HWSZ);
        f4 M  = *(const f4*)(tp + oM);
        f4 Lg = pL ? *(const f4*)(tp + oM - 4) : z4;
        f4 Rg = pR ? *(const f4*)(tp + oM + 4) : z4;

        f4 U[RR], D[RR];
#pragma unroll
        for (int i = 1; i <= RR; ++i) {
            U[i - 1] = pu[i] ? *(const f4*)(tp + oM - i * WW) : z4;
            D[i - 1] = pd[i] ? *(const f4*)(tp + oM + i * WW) : z4;
        }

        const float sv[4] = {s4.x, s4.y, s4.z, s4.w};
        const float lm[8] = {Lg.x, Lg.y, Lg.z, Lg.w, M.x, M.y, M.z, M.w};
        const float mr[8] = {M.x, M.y, M.z, M.w, Rg.x, Rg.y, Rg.z, Rg.w};
        const float uu[RR][4] = {{U[0].x, U[0].y, U[0].z, U[0].w},
                                 {U[1].x, U[1].y, U[1].z, U[1].w},
                                 {U[2].x, U[2].y, U[2].z, U[2].w},
                                 {U[3].x, U[3].y, U[3].z, U[3].w}};
        const float dd[RR][4] = {{D[0].x, D[0].y, D[0].z, D[0].w},
                                 {D[1].x, D[1].y, D[1].z, D[1].w},
                                 {D[2].x, D[2].y, D[2].z, D[2].w},
                                 {D[3].x, D[3].y, D[3].z, D[3].w}};

        // s=0: center (dh=0, dw=0)
#pragma unroll
        for (int j = 0; j < 4; ++j) acc[0][j] = fmaf(sv[j], lm[4 + j], acc[0][j]);

        // s=4i-3: dh=-i (up) | s=4i-2: dh=+i (down) | s=4i-1: dw=-i | s=4i: dw=+i
#pragma unroll
        for (int i = 1; i <= RR; ++i) {
#pragma unroll
            for (int j = 0; j < 4; ++j) {
                acc[4 * i - 3][j] = fmaf(sv[j], uu[i - 1][j],  acc[4 * i - 3][j]);
                acc[4 * i - 2][j] = fmaf(sv[j], dd[i - 1][j],  acc[4 * i - 2][j]);
                acc[4 * i - 1][j] = fmaf(sv[j], lm[4 + j - i], acc[4 * i - 1][j]);
                acc[4 * i    ][j] = fmaf(sv[j], mr[j + i],     acc[4 * i    ][j]);
            }
        }
    }

    // epilogue: 8 chunk-blocks accumulate atomically per output
#pragma unroll
    for (int s = 0; s < NS; ++s) {
        float* op = out + (((size_t)(b * NS + s)) * HH + r) * WW + cb;
#pragma unroll
        for (int j = 0; j < 4; ++j) atomicAdd(op + j, acc[s][j]);
    }
}

extern "C" void kernel_launch(void* const* d_in, const int* in_sizes, int n_in,
                              void* d_out, int out_size, void* d_ws, size_t ws_size,
                              hipStream_t stream) {
    const float* src = (const float*)d_in[0];
    const float* tgt = (const float*)d_in[1];
    float* out = (float*)d_out;

    // out is poisoned 0xAA before every launch; we accumulate atomically -> zero it
    hipMemsetAsync(out, 0, (size_t)out_size * sizeof(float), stream);

    dim3 block(8, 32, 1);                        // 256 threads, 4 waves
    dim3 grid(WW / TW, HH / THT, BB * NCHUNK);   // (5, 3, 32) = 480 blocks
    cost_volume_kernel<<<grid, block, 0, stream>>>(src, tgt, out);
}

// Round 6
// 129.867 us; speedup vs baseline: 1.8414x; 1.8414x over previous
//
#include <hip/hip_runtime.h>

#define RR 4
#define NS 17
#define BB 4
#define CC 128
#define HH 96
#define WW 160
#define HWSZ (HH * WW)

// Stage 1: R4's proven structure (LDS group staging, conflict-free b32 reads),
// but partials go to ws with PLAIN STORES (chunk-major) — zero atomics.
// Stage 2: out = sum of NCHUNK partials, float4 elementwise.
#define TW 32
#define THT 16
#define TROWS 24
#define TCOLS 40
#define CH_F4 (TROWS * TCOLS / 4)  // 240 float4 per channel tile
#define G 4                        // channels staged per barrier pair
#define CCHUNK 32
#define NCHUNK (CC / CCHUNK)       // 4 partials per output
#define NGROUP (CCHUNK / G)        // 8
#define NSLOT (G * CH_F4)          // 960 float4 per group
#define OUTN (BB * NS * HH * WW)   // 1,044,480
#define OUTF4 (OUTN / 4)           // 261,120

typedef float4 f4;

__global__ __launch_bounds__(256, 4)
void cost_volume_partial(const float* __restrict__ src,
                         const float* __restrict__ tgt,
                         float* __restrict__ ws) {
    __shared__ __align__(16) float tile[G][TROWS][TCOLS];  // 15360 B

    const int x   = threadIdx.x;          // 0..31 (col)
    const int ty  = threadIdx.y;          // 0..7  (row pair)
    const int tid = ty * TW + x;          // 0..255

    const int w0    = blockIdx.x * TW;
    const int h0    = blockIdx.y * THT;
    const int b     = blockIdx.z & 3;
    const int chunk = blockIdx.z >> 2;
    const int c0    = chunk * CCHUNK;

    const float* tgt_b = tgt + (size_t)(b * CC) * HWSZ;
    const float* src_b = src + (size_t)(b * CC) * HWSZ;

    // ---- channel-group-invariant staging geometry (4 f4 slots/thread) ----
    int  soff[4];
    bool sval[4];
#pragma unroll
    for (int k = 0; k < 4; ++k) {
        int s   = tid + k * 256;
        int ch  = s / CH_F4;               // 0..3 within group
        int idx = s - ch * CH_F4;
        int r   = idx / 10;                // 10 f4 per tile row
        int c   = idx - 10 * r;
        int gr  = h0 - RR + r;
        int gc  = w0 - RR + 4 * c;         // f4 all-in or all-out (halo=4)
        sval[k] = (s < NSLOT) && (gr >= 0) && (gr < HH) && (gc >= 0) && (gc <= WW - 4);
        soff[k] = ch * HWSZ + gr * WW + gc;
    }
    const float* srow = src_b + (h0 + 2 * ty) * WW + (w0 + x);
    const f4 zero4 = make_float4(0.f, 0.f, 0.f, 0.f);

    float acc[2][NS];
#pragma unroll
    for (int i = 0; i < 2; ++i)
#pragma unroll
        for (int s = 0; s < NS; ++s) acc[i][s] = 0.f;

    f4 P[4];
    float S[G][2];

    auto load_group = [&](int g) {
        const float* tg = tgt_b + (size_t)(c0 + g * G) * HWSZ;
#pragma unroll
        for (int k = 0; k < 4; ++k)
            P[k] = sval[k] ? *(const f4*)(tg + soff[k]) : zero4;
        const float* sg = srow + (size_t)(c0 + g * G) * HWSZ;
#pragma unroll
        for (int ch = 0; ch < G; ++ch) {
            S[ch][0] = sg[(size_t)ch * HWSZ];
            S[ch][1] = sg[(size_t)ch * HWSZ + WW];
        }
    };

    load_group(0);

    for (int g = 0; g < NGROUP; ++g) {
        // stage group g (loads issued a full compute phase ago)
#pragma unroll
        for (int k = 0; k < 4; ++k) {
            int s = tid + k * 256;
            if (s < NSLOT) ((f4*)tile)[s] = P[k];
        }
        float sc[G][2];
#pragma unroll
        for (int ch = 0; ch < G; ++ch) { sc[ch][0] = S[ch][0]; sc[ch][1] = S[ch][1]; }
        __syncthreads();

        if (g + 1 < NGROUP) load_group(g + 1);

        // compute 4 channels: ds_read_b32 w/ immediate offsets, conflict-free
#pragma unroll
        for (int ch = 0; ch < G; ++ch) {
            float v[10];  // column (RR+x), rows 2ty .. 2ty+9
#pragma unroll
            for (int k = 0; k < 10; ++k) v[k] = tile[ch][2 * ty + k][RR + x];
#pragma unroll
            for (int i = 0; i < 2; ++i) {
                const float sv = sc[ch][i];
                acc[i][0] = fmaf(sv, v[4 + i], acc[i][0]);
#pragma unroll
                for (int off = 1; off <= RR; ++off) {
                    acc[i][4 * off - 3] = fmaf(sv, v[4 + i - off], acc[i][4 * off - 3]);  // up
                    acc[i][4 * off - 2] = fmaf(sv, v[4 + i + off], acc[i][4 * off - 2]);  // down
                }
            }
#pragma unroll
            for (int i = 0; i < 2; ++i) {
                const float sv = sc[ch][i];
                const float* row = &tile[ch][RR + 2 * ty + i][RR + x];
#pragma unroll
                for (int off = 1; off <= RR; ++off) {
                    acc[i][4 * off - 1] = fmaf(sv, row[-off], acc[i][4 * off - 1]);  // left
                    acc[i][4 * off    ] = fmaf(sv, row[ off], acc[i][4 * off    ]);  // right
                }
            }
        }
        __syncthreads();
    }

    // epilogue: PLAIN stores of this chunk's partial into ws (chunk-major)
    float* wbase = ws + (size_t)chunk * OUTN;
#pragma unroll
    for (int i = 0; i < 2; ++i) {
        const int h = h0 + 2 * ty + i;
#pragma unroll
        for (int s = 0; s < NS; ++s) {
            wbase[(((size_t)(b * NS + s)) * HH + h) * WW + w0 + x] = acc[i][s];
        }
    }
}

__global__ __launch_bounds__(256)
void cost_volume_reduce(const float* __restrict__ ws, float* __restrict__ out) {
    const int i = blockIdx.x * 256 + threadIdx.x;  // f4 index, grid sized exactly
    const f4* a = (const f4*)ws;
    f4 r0 = a[i];
    f4 r1 = a[i + OUTF4];
    f4 r2 = a[i + 2 * OUTF4];
    f4 r3 = a[i + 3 * OUTF4];
    f4 o;
    o.x = (r0.x + r1.x) + (r2.x + r3.x);
    o.y = (r0.y + r1.y) + (r2.y + r3.y);
    o.z = (r0.z + r1.z) + (r2.z + r3.z);
    o.w = (r0.w + r1.w) + (r2.w + r3.w);
    ((f4*)out)[i] = o;
}

extern "C" void kernel_launch(void* const* d_in, const int* in_sizes, int n_in,
                              void* d_out, int out_size, void* d_ws, size_t ws_size,
                              hipStream_t stream) {
    const float* src = (const float*)d_in[0];
    const float* tgt = (const float*)d_in[1];
    float* out = (float*)d_out;
    float* ws  = (float*)d_ws;   // needs NCHUNK*OUTN*4 = 16.7 MB

    dim3 block1(TW, 8, 1);                         // 256 threads, 4 waves
    dim3 grid1(WW / TW, HH / THT, BB * NCHUNK);    // (5, 6, 16) = 480 blocks
    cost_volume_partial<<<grid1, block1, 0, stream>>>(src, tgt, ws);

    cost_volume_reduce<<<OUTF4 / 256, 256, 0, stream>>>(ws, out);  // 1020 blocks
}